// Round 5
// baseline (240.583 us; speedup 1.0000x reference)
//
#include <hip/hip_runtime.h>

// Problem: B=8, C=256, T=16, H=28, W=28
//   h_t = 0.5*(W @ h_{t-1} + x_t)   (channel matmul per spatial position)
//   out[:,:,0] = x0; out[:,:,t] = h_t
//
// 392 blocks of 16 spatial columns; h round-trips through double-buffered
// bf16 LDS; W preloaded as MFMA A-fragments; x double-buffered in LDS via
// global_load_lds one step ahead; counted-vmcnt + LDS-only barriers.
//
// THIS VERSION: occupancy x2 (the single changed axis). Rounds 0-4 showed
// four different sync/prefetch structures all identical at ~98-103us,
// 2.3 TB/s, Occupancy 13% -- the limiter is resident-wave MLP, not sync:
// grid 392 x 4 waves / 256 CUs = only ~6 waves/CU peak. Now: 512-thread
// blocks (8 waves, 32 channels/wave). Per-wave A-fragments halve to 64
// VGPRs -> launch_bounds(512,4) keeps VGPR<=128 so dual-block CUs hold all
// 16 waves resident (~12 waves/CU average, 2x prior). Same tiles, same
// traffic, same sync discipline.

typedef __attribute__((ext_vector_type(8))) short bf16x8;  // 8 bf16 = 4 VGPRs
typedef __attribute__((ext_vector_type(4))) float f32x4;
typedef __attribute__((ext_vector_type(4))) short short4v;

#define NTILES 49       // 784 / 16 spatial tiles per batch
#define LDSK   264      // 256 + 8 bf16 pad -> stride 528 B

// async global->LDS, 16B per lane; LDS dest is wave-uniform base + lane*16
#define ASYNC16(gsrc, ldst)                                                    \
    __builtin_amdgcn_global_load_lds(                                          \
        (const __attribute__((address_space(1))) void*)(gsrc),                 \
        (__attribute__((address_space(3))) void*)(ldst), 16, 0, 0)

// Raw LDS-only barrier: drain this wave's LDS ops, then s_barrier.
// NO vmcnt drain -- in-flight global loads/stores survive the barrier.
#define LDS_BARRIER()                                                          \
    do {                                                                       \
        asm volatile("s_waitcnt lgkmcnt(0)" ::: "memory");                     \
        __builtin_amdgcn_s_barrier();                                          \
        __builtin_amdgcn_sched_barrier(0);                                     \
    } while (0)

// Counted VMEM wait: everything except the N newest VMEM ops has retired.
// N=10: the 2 just-issued x(t+1) prefetch loads + the 8 stores of step t-1
// may stay in flight; everything older (x(t) prefetch) must have landed.
#define WAIT_VMCNT_10()                                                        \
    do {                                                                       \
        asm volatile("s_waitcnt vmcnt(10)" ::: "memory");                      \
        __builtin_amdgcn_sched_barrier(0);                                     \
    } while (0)

__device__ __forceinline__ short f2bf(float f) {
    // round-to-nearest-even fp32 -> bf16 (inputs finite)
    union { float f; unsigned u; } v; v.f = f;
    unsigned r = v.u + 0x7FFFu + ((v.u >> 16) & 1u);
    return (short)(r >> 16);
}

__global__ __launch_bounds__(512, 4)
void rcu_kernel(const float* __restrict__ in, const float* __restrict__ Wm,
                float* __restrict__ out) {
    // h double-buffer, bf16 [n=16][k=256(+8)] : 16896 B
    __shared__ short hbuf[2][16][LDSK];
    // x double-buffer, fp32 [c=256][s=16] : 32768 B (linear; global_load_lds
    // lane order: lane l of issue (w,i) -> chan w*32+i*16 + l/4, spat quad l%4)
    __shared__ float xlds[2][256][16];

    const int tid  = threadIdx.x;
    const int wave = tid >> 6;      // 8 waves: wave w owns channels [w*32, w*32+32)
    const int lane = tid & 63;
    const int l15  = lane & 15;
    const int quad = lane >> 4;

    const int b  = blockIdx.x / NTILES;
    const int s0 = (blockIdx.x % NTILES) * 16;

    // Flat index: ((b*256 + c)*16 + t)*784 + s ;  c-stride = 12544 floats
    const size_t base = (size_t)b * 256 * 16 * 784 + s0;
    const float* xin  = in  + base;
    float*       xout = out + base;

    // per-lane source decomposition for the async copies (wave-local channels)
    const int cidx = lane >> 2;         // channel within a 16-channel chunk
    const int sq   = (lane & 3) * 4;    // spatial float4 within the 16-col tile

    // ---- issue x(t=0) prefetch into xlds[0] (2 issues/wave) ----
#pragma unroll
    for (int i = 0; i < 2; ++i) {
        const int cbi = wave * 32 + i * 16;
        ASYNC16(xin + (size_t)(cbi + cidx) * 12544 + sq, &xlds[0][cbi][0]);
    }

    // ---- Preload W as bf16 A-fragments (once; reused for all 15 steps) ----
    // A[m][k]: m = lane&15 (+tile base), k = quad*8 + j
    bf16x8 a_frag[2][8];            // 2 m-tiles x 8 k-steps = 64 VGPRs
#pragma unroll
    for (int mt = 0; mt < 2; ++mt) {
        const int m = wave * 32 + mt * 16 + l15;
        const float* wrow = Wm + m * 256 + quad * 8;
#pragma unroll
        for (int ks = 0; ks < 8; ++ks) {
            float4 f0 = *(const float4*)(wrow + ks * 32);
            float4 f1 = *(const float4*)(wrow + ks * 32 + 4);
            bf16x8 a;
            a[0] = f2bf(f0.x); a[1] = f2bf(f0.y); a[2] = f2bf(f0.z); a[3] = f2bf(f0.w);
            a[4] = f2bf(f1.x); a[5] = f2bf(f1.y); a[6] = f2bf(f1.z); a[7] = f2bf(f1.w);
            a_frag[mt][ks] = a;
        }
    }

    // ---- issue x(t=1) prefetch into xlds[1] ----
#pragma unroll
    for (int i = 0; i < 2; ++i) {
        const int cbi = wave * 32 + i * 16;
        ASYNC16(xin + (size_t)(cbi + cidx) * 12544 + 784 + sq, &xlds[1][cbi][0]);
    }

    // Prologue barrier: full drain once (x0/x1 landed; xlds published for the
    // cross-wave init reads below).
    __syncthreads();

    // ---- Init from xlds[0]: out(t=0) passthrough + stage h0 into hbuf[0] ----
    {
        const int sg = tid & 15;      // spatial within tile
        const int cg = tid >> 4;      // channel group 0..31
#pragma unroll
        for (int i = 0; i < 8; ++i) {
            const int c = cg * 8 + i;
            const float v = xlds[0][c][sg];
            xout[(size_t)c * 12544 + sg] = v;       // t = 0
            hbuf[0][sg][c] = f2bf(v);
        }
    }
    // Publishes hbuf[0]; guarantees all cross-wave xlds[0] reads complete
    // before step t=1's prefetch overwrites xlds[0]. Init stores in flight.
    LDS_BARRIER();

    int cur = 0;
#pragma unroll
    for (int t = 1; t < 16; ++t) {
        const int xb = t & 1;        // xlds buffer holding x(t)

        // ---- prefetch x(t+1); survives this step's barrier, consumed at
        //      the end of step t+1
        if (t < 15) {
#pragma unroll
            for (int i = 0; i < 2; ++i) {
                const int cbi = wave * 32 + i * 16;
                ASYNC16(xin + (size_t)(cbi + cidx) * 12544 + (size_t)(t + 1) * 784 + sq,
                        &xlds[xb ^ 1][cbi][0]);
            }
        }

        // B fragments from LDS: B[k][n], k = ks*32 + quad*8 + j, n = lane&15
        bf16x8 bfrag[8];
        const short* hp = &hbuf[cur][l15][quad * 8];
#pragma unroll
        for (int ks = 0; ks < 8; ++ks)
            bfrag[ks] = *(const bf16x8*)(hp + ks * 32);   // ds_read_b128

        f32x4 acc[2];
#pragma unroll
        for (int mt = 0; mt < 2; ++mt) {
            acc[mt] = (f32x4){0.f, 0.f, 0.f, 0.f};
#pragma unroll
            for (int ks = 0; ks < 8; ++ks)
                acc[mt] = __builtin_amdgcn_mfma_f32_16x16x32_bf16(
                    a_frag[mt][ks], bfrag[ks], acc[mt], 0, 0, 0);
        }

        // x(t) landed? Newest 10 VMEM ops (2 prefetch + 8 prior stores) may
        // remain outstanding; xlds is wave-local -> no barrier needed.
        WAIT_VMCNT_10();

        const int nxt = cur ^ 1;
#pragma unroll
        for (int mt = 0; mt < 2; ++mt) {
            // D layout: row(channel within tile) = quad*4 + r, col = lane&15
            const int c0 = wave * 32 + mt * 16 + quad * 4;
            short4v hbf;
#pragma unroll
            for (int r = 0; r < 4; ++r) {
                const float xv = xlds[xb][c0 + r][l15];            // LDS
                const float v  = 0.5f * (acc[mt][r] + xv);
                xout[((size_t)(c0 + r) * 16 + t) * 784 + l15] = v; // fire&forget
                hbf[r] = f2bf(v);
            }
            // 4 consecutive channels -> one 8B LDS write
            *(short4v*)&hbuf[nxt][l15][c0] = hbf;
        }
        // Publish hbuf[nxt]; in-flight prefetch + stores survive the barrier.
        LDS_BARRIER();
        cur = nxt;
    }
}

extern "C" void kernel_launch(void* const* d_in, const int* in_sizes, int n_in,
                              void* d_out, int out_size, void* d_ws, size_t ws_size,
                              hipStream_t stream) {
    const float* in  = (const float*)d_in[0];
    const float* Wm  = (const float*)d_in[1];
    float*       out = (float*)d_out;
    hipLaunchKernelGGL(rcu_kernel, dim3(8 * NTILES), dim3(512), 0, stream, in, Wm, out);
}

// Round 6
// 209.490 us; speedup vs baseline: 1.1484x; 1.1484x over previous
//
#include <hip/hip_runtime.h>

// Problem: B=8, C=256, T=16, H=28, W=28
//   h_t = 0.5*(W @ h_{t-1} + x_t)   (channel matmul per spatial position)
//   out[:,:,0] = x0; out[:,:,t] = h_t
//
// THIS VERSION: 32-column tiles (single changed axis vs rounds 0-5's 16-col).
// Five sync/occupancy variants all pinned at ~2.3-2.5 TB/s with 64 B
// segments (half an L2 line, other half owned by another block on another
// XCD -> partial-line writebacks, write-allocate fetches, DRAM page
// thrashing; WRITE_SIZE inflated to 1.4x ideal in round 5). 32-col tiles
// give 128 B line-ALIGNED segments: zero cross-block line sharing, half the
// page sharers. 784 = 24*32 + 16 -> 25 tiles/batch (tail tile is 16-col via
// template<NT>), grid = 200 blocks x 512 threads (8 waves, 32 chan/wave).
// x in registers (round-3-proven equal to LDS prefetch), 1 step ahead;
// h in double-buffered bf16 LDS; per-step sync = lgkmcnt(0)+s_barrier only.

typedef __attribute__((ext_vector_type(8))) short bf16x8;  // 8 bf16 = 4 VGPRs
typedef __attribute__((ext_vector_type(4))) float f32x4;
typedef __attribute__((ext_vector_type(4))) short short4v;

#define TILES_PER_B 25   // 24 full 32-col tiles + 1 tail 16-col tile
#define LDSK 264         // 256 + 8 bf16 pad -> row stride 528 B

// Raw LDS-only barrier: drain this wave's LDS ops, then s_barrier.
// NO vmcnt drain -- in-flight global loads/stores survive the barrier.
#define LDS_BARRIER()                                                          \
    do {                                                                       \
        asm volatile("s_waitcnt lgkmcnt(0)" ::: "memory");                     \
        __builtin_amdgcn_s_barrier();                                          \
        __builtin_amdgcn_sched_barrier(0);                                     \
    } while (0)

__device__ __forceinline__ short f2bf(float f) {
    // round-to-nearest-even fp32 -> bf16 (inputs finite)
    union { float f; unsigned u; } v; v.f = f;
    unsigned r = v.u + 0x7FFFu + ((v.u >> 16) & 1u);
    return (short)(r >> 16);
}

// NT = number of 16-col n-tiles this block owns (2 = full 32-col, 1 = tail).
template <int NT>
__device__ __forceinline__ void run_tile(const float* __restrict__ xin,
                                         float* __restrict__ xout,
                                         const float* __restrict__ Wm,
                                         short (*hbuf)[32][LDSK]) {
    const int tid  = threadIdx.x;
    const int wave = tid >> 6;      // 8 waves: wave w owns channels [w*32, w*32+32)
    const int lane = tid & 63;
    const int l15  = lane & 15;
    const int quad = lane >> 4;

    // ---- Preload W as bf16 A-fragments (once; reused for all 15 steps) ----
    // A[m][k]: m = lane&15 (+tile base), k = quad*8 + j
    bf16x8 a_frag[2][8];            // 2 m-tiles x 8 k-steps = 64 VGPRs
#pragma unroll
    for (int mt = 0; mt < 2; ++mt) {
        const int m = wave * 32 + mt * 16 + l15;
        const float* wrow = Wm + m * 256 + quad * 8;
#pragma unroll
        for (int ks = 0; ks < 8; ++ks) {
            float4 f0 = *(const float4*)(wrow + ks * 32);
            float4 f1 = *(const float4*)(wrow + ks * 32 + 4);
            bf16x8 a;
            a[0] = f2bf(f0.x); a[1] = f2bf(f0.y); a[2] = f2bf(f0.z); a[3] = f2bf(f0.w);
            a[4] = f2bf(f1.x); a[5] = f2bf(f1.y); a[6] = f2bf(f1.z); a[7] = f2bf(f1.w);
            a_frag[mt][ks] = a;
        }
    }

    // ---- Init: h0 = x(t=0); passthrough to out; stage bf16 into hbuf[0] ----
    {
        const int NS  = 16 * NT;          // spatial width of this tile
        const int sg  = tid & (NS - 1);   // spatial within tile
        const int cg  = tid / NS;         // channel group
        const int CPT = NS / 2;           // channels per thread (16 or 8)
#pragma unroll
        for (int i = 0; i < CPT; ++i) {
            const int c = cg * CPT + i;
            const size_t off = (size_t)c * 12544 + sg;   // t = 0
            const float v = xin[off];
            xout[off] = v;
            hbuf[0][sg][c] = f2bf(v);
        }
    }

    // x value ring, 1-step prefetch depth; all indices static after unroll.
    // slot (mt,nt,r) -> channel c = wave*32 + mt*16 + quad*4 + r,
    //                   spatial s = nt*16 + l15
    float xr[2][2][NT][4];

    // preload x(t=1)
#pragma unroll
    for (int mt = 0; mt < 2; ++mt)
#pragma unroll
        for (int nt = 0; nt < NT; ++nt)
#pragma unroll
            for (int r = 0; r < 4; ++r) {
                const int c = wave * 32 + mt * 16 + quad * 4 + r;
                xr[1][mt][nt][r] = xin[((size_t)c * 16 + 1) * 784 + nt * 16 + l15];
            }

    // publish hbuf[0] (cross-wave); init stores/loads stay in flight
    LDS_BARRIER();

    int cur = 0;
#pragma unroll
    for (int t = 1; t < 16; ++t) {
        const int xb = t & 1;        // xr slot holding x(t)

        // ---- prefetch x(t+1) into the other ring slot (plain global loads;
        //      retired ~one full step later by the compiler's counted vmcnt)
        if (t < 15) {
#pragma unroll
            for (int mt = 0; mt < 2; ++mt)
#pragma unroll
                for (int nt = 0; nt < NT; ++nt)
#pragma unroll
                    for (int r = 0; r < 4; ++r) {
                        const int c = wave * 32 + mt * 16 + quad * 4 + r;
                        xr[xb ^ 1][mt][nt][r] =
                            xin[((size_t)c * 16 + t + 1) * 784 + nt * 16 + l15];
                    }
        }

        // B fragments from LDS: B[k][n], k = ks*32 + quad*8 + j,
        // n = nt*16 + (lane&15)
        bf16x8 bfrag[NT][8];
#pragma unroll
        for (int nt = 0; nt < NT; ++nt) {
            const short* hp = &hbuf[cur][nt * 16 + l15][quad * 8];
#pragma unroll
            for (int ks = 0; ks < 8; ++ks)
                bfrag[nt][ks] = *(const bf16x8*)(hp + ks * 32);   // ds_read_b128
        }

        f32x4 acc[2][NT];
#pragma unroll
        for (int mt = 0; mt < 2; ++mt)
#pragma unroll
            for (int nt = 0; nt < NT; ++nt) {
                acc[mt][nt] = (f32x4){0.f, 0.f, 0.f, 0.f};
#pragma unroll
                for (int ks = 0; ks < 8; ++ks)
                    acc[mt][nt] = __builtin_amdgcn_mfma_f32_16x16x32_bf16(
                        a_frag[mt][ks], bfrag[nt][ks], acc[mt][nt], 0, 0, 0);
            }

        const int nxt = cur ^ 1;
#pragma unroll
        for (int mt = 0; mt < 2; ++mt) {
            // D layout: row(channel within tile) = quad*4 + r, col = lane&15
            const int c0 = wave * 32 + mt * 16 + quad * 4;
#pragma unroll
            for (int nt = 0; nt < NT; ++nt) {
                short4v hbf;
#pragma unroll
                for (int r = 0; r < 4; ++r) {
                    const float v = 0.5f * (acc[mt][nt][r] + xr[xb][mt][nt][r]);
                    xout[((size_t)(c0 + r) * 16 + t) * 784 + nt * 16 + l15] = v;
                    hbf[r] = f2bf(v);
                }
                // 4 consecutive channels -> one 8B LDS write
                *(short4v*)&hbuf[nxt][nt * 16 + l15][c0] = hbf;
            }
        }
        // Publish hbuf[nxt]; in-flight loads + stores survive the barrier.
        LDS_BARRIER();
        cur = nxt;
    }
}

__global__ __launch_bounds__(512, 2)
void rcu_kernel(const float* __restrict__ in, const float* __restrict__ Wm,
                float* __restrict__ out) {
    // h double-buffer, bf16 [n=32][k=256(+8)] : 33792 B (only LDS use)
    __shared__ short hbuf[2][32][LDSK];

    const int b = blockIdx.x / TILES_PER_B;
    const int j = blockIdx.x % TILES_PER_B;
    const size_t base = (size_t)b * 256 * 16 * 784 + (size_t)j * 32;

    if (j < 24) run_tile<2>(in + base, out + base, Wm, hbuf);
    else        run_tile<1>(in + base, out + base, Wm, hbuf);
}

extern "C" void kernel_launch(void* const* d_in, const int* in_sizes, int n_in,
                              void* d_out, int out_size, void* d_ws, size_t ws_size,
                              hipStream_t stream) {
    const float* in  = (const float*)d_in[0];
    const float* Wm  = (const float*)d_in[1];
    float*       out = (float*)d_out;
    hipLaunchKernelGGL(rcu_kernel, dim3(8 * TILES_PER_B), dim3(512), 0, stream,
                       in, Wm, out);
}

// Round 7
// 208.996 us; speedup vs baseline: 1.1511x; 1.0024x over previous
//
#include <hip/hip_runtime.h>

// Problem: B=8, C=256, T=16, H=28, W=28
//   h_t = 0.5*(W @ h_{t-1} + x_t)   (channel matmul per spatial position)
//   out[:,:,0] = x0; out[:,:,t] = h_t
//
// Round-6 structure (32-col tiles, 200 blocks x 512 threads, x in registers
// 1 step ahead, h in double-buffered bf16 LDS, lgkmcnt-only barriers).
//
// THIS VERSION (single axis): ALL output stores are NON-TEMPORAL.
// Rationale: six structural variants (sync, prefetch, occupancy, segment
// geometry) all pin at 2.2-2.5 TB/s while pipes are ~93% idle. Round 6
// showed FETCH_SIZE (77 MB) already below the compulsory input size
// (103 MB): L3 retains input across dispatches, but 101 MB of ALLOCATING
// stores keeps evicting it and emits dirty write-backs in scattered set
// order, and the fine R/W interleave defeats DRAM burst scheduling.
// NT stores bypass L2/L3 allocation: writes stream to DRAM in issue order
// (clean 64 B bursts), L3 becomes a read-mostly cache holding the whole
// input, reads turn into L3 hits. out is never re-read in-kernel, so nt is
// semantically safe.

typedef __attribute__((ext_vector_type(8))) short bf16x8;  // 8 bf16 = 4 VGPRs
typedef __attribute__((ext_vector_type(4))) float f32x4;
typedef __attribute__((ext_vector_type(4))) short short4v;

#define TILES_PER_B 25   // 24 full 32-col tiles + 1 tail 16-col tile
#define LDSK 264         // 256 + 8 bf16 pad -> row stride 528 B

// Raw LDS-only barrier: drain this wave's LDS ops, then s_barrier.
// NO vmcnt drain -- in-flight global loads/stores survive the barrier.
#define LDS_BARRIER()                                                          \
    do {                                                                       \
        asm volatile("s_waitcnt lgkmcnt(0)" ::: "memory");                     \
        __builtin_amdgcn_s_barrier();                                          \
        __builtin_amdgcn_sched_barrier(0);                                     \
    } while (0)

__device__ __forceinline__ short f2bf(float f) {
    // round-to-nearest-even fp32 -> bf16 (inputs finite)
    union { float f; unsigned u; } v; v.f = f;
    unsigned r = v.u + 0x7FFFu + ((v.u >> 16) & 1u);
    return (short)(r >> 16);
}

// NT = number of 16-col n-tiles this block owns (2 = full 32-col, 1 = tail).
template <int NT>
__device__ __forceinline__ void run_tile(const float* __restrict__ xin,
                                         float* __restrict__ xout,
                                         const float* __restrict__ Wm,
                                         short (*hbuf)[32][LDSK]) {
    const int tid  = threadIdx.x;
    const int wave = tid >> 6;      // 8 waves: wave w owns channels [w*32, w*32+32)
    const int lane = tid & 63;
    const int l15  = lane & 15;
    const int quad = lane >> 4;

    // ---- Preload W as bf16 A-fragments (once; reused for all 15 steps) ----
    // A[m][k]: m = lane&15 (+tile base), k = quad*8 + j
    bf16x8 a_frag[2][8];            // 2 m-tiles x 8 k-steps = 64 VGPRs
#pragma unroll
    for (int mt = 0; mt < 2; ++mt) {
        const int m = wave * 32 + mt * 16 + l15;
        const float* wrow = Wm + m * 256 + quad * 8;
#pragma unroll
        for (int ks = 0; ks < 8; ++ks) {
            float4 f0 = *(const float4*)(wrow + ks * 32);
            float4 f1 = *(const float4*)(wrow + ks * 32 + 4);
            bf16x8 a;
            a[0] = f2bf(f0.x); a[1] = f2bf(f0.y); a[2] = f2bf(f0.z); a[3] = f2bf(f0.w);
            a[4] = f2bf(f1.x); a[5] = f2bf(f1.y); a[6] = f2bf(f1.z); a[7] = f2bf(f1.w);
            a_frag[mt][ks] = a;
        }
    }

    // ---- Init: h0 = x(t=0); passthrough to out (NT); stage into hbuf[0] ----
    {
        const int NS  = 16 * NT;          // spatial width of this tile
        const int sg  = tid & (NS - 1);   // spatial within tile
        const int cg  = tid / NS;         // channel group
        const int CPT = NS / 2;           // channels per thread (16 or 8)
#pragma unroll
        for (int i = 0; i < CPT; ++i) {
            const int c = cg * CPT + i;
            const size_t off = (size_t)c * 12544 + sg;   // t = 0
            const float v = xin[off];
            __builtin_nontemporal_store(v, &xout[off]);
            hbuf[0][sg][c] = f2bf(v);
        }
    }

    // x value ring, 1-step prefetch depth; all indices static after unroll.
    // slot (mt,nt,r) -> channel c = wave*32 + mt*16 + quad*4 + r,
    //                   spatial s = nt*16 + l15
    float xr[2][2][NT][4];

    // preload x(t=1)  (normal loads: allocate in L2/L3)
#pragma unroll
    for (int mt = 0; mt < 2; ++mt)
#pragma unroll
        for (int nt = 0; nt < NT; ++nt)
#pragma unroll
            for (int r = 0; r < 4; ++r) {
                const int c = wave * 32 + mt * 16 + quad * 4 + r;
                xr[1][mt][nt][r] = xin[((size_t)c * 16 + 1) * 784 + nt * 16 + l15];
            }

    // publish hbuf[0] (cross-wave); init stores/loads stay in flight
    LDS_BARRIER();

    int cur = 0;
#pragma unroll
    for (int t = 1; t < 16; ++t) {
        const int xb = t & 1;        // xr slot holding x(t)

        // ---- prefetch x(t+1) into the other ring slot (plain global loads;
        //      retired ~one full step later by the compiler's counted vmcnt)
        if (t < 15) {
#pragma unroll
            for (int mt = 0; mt < 2; ++mt)
#pragma unroll
                for (int nt = 0; nt < NT; ++nt)
#pragma unroll
                    for (int r = 0; r < 4; ++r) {
                        const int c = wave * 32 + mt * 16 + quad * 4 + r;
                        xr[xb ^ 1][mt][nt][r] =
                            xin[((size_t)c * 16 + t + 1) * 784 + nt * 16 + l15];
                    }
        }

        // B fragments from LDS: B[k][n], k = ks*32 + quad*8 + j,
        // n = nt*16 + (lane&15)
        bf16x8 bfrag[NT][8];
#pragma unroll
        for (int nt = 0; nt < NT; ++nt) {
            const short* hp = &hbuf[cur][nt * 16 + l15][quad * 8];
#pragma unroll
            for (int ks = 0; ks < 8; ++ks)
                bfrag[nt][ks] = *(const bf16x8*)(hp + ks * 32);   // ds_read_b128
        }

        f32x4 acc[2][NT];
#pragma unroll
        for (int mt = 0; mt < 2; ++mt)
#pragma unroll
            for (int nt = 0; nt < NT; ++nt) {
                acc[mt][nt] = (f32x4){0.f, 0.f, 0.f, 0.f};
#pragma unroll
                for (int ks = 0; ks < 8; ++ks)
                    acc[mt][nt] = __builtin_amdgcn_mfma_f32_16x16x32_bf16(
                        a_frag[mt][ks], bfrag[nt][ks], acc[mt][nt], 0, 0, 0);
            }

        const int nxt = cur ^ 1;
#pragma unroll
        for (int mt = 0; mt < 2; ++mt) {
            // D layout: row(channel within tile) = quad*4 + r, col = lane&15
            const int c0 = wave * 32 + mt * 16 + quad * 4;
#pragma unroll
            for (int nt = 0; nt < NT; ++nt) {
                short4v hbf;
#pragma unroll
                for (int r = 0; r < 4; ++r) {
                    const float v = 0.5f * (acc[mt][nt][r] + xr[xb][mt][nt][r]);
                    __builtin_nontemporal_store(
                        v, &xout[((size_t)(c0 + r) * 16 + t) * 784 + nt * 16 + l15]);
                    hbf[r] = f2bf(v);
                }
                // 4 consecutive channels -> one 8B LDS write
                *(short4v*)&hbuf[nxt][nt * 16 + l15][c0] = hbf;
            }
        }
        // Publish hbuf[nxt]; in-flight loads + stores survive the barrier.
        LDS_BARRIER();
        cur = nxt;
    }
}

__global__ __launch_bounds__(512, 2)
void rcu_kernel(const float* __restrict__ in, const float* __restrict__ Wm,
                float* __restrict__ out) {
    // h double-buffer, bf16 [n=32][k=256(+8)] : 33792 B (only LDS use)
    __shared__ short hbuf[2][32][LDSK];

    const int b = blockIdx.x / TILES_PER_B;
    const int j = blockIdx.x % TILES_PER_B;
    const size_t base = (size_t)b * 256 * 16 * 784 + (size_t)j * 32;

    if (j < 24) run_tile<2>(in + base, out + base, Wm, hbuf);
    else        run_tile<1>(in + base, out + base, Wm, hbuf);
}

extern "C" void kernel_launch(void* const* d_in, const int* in_sizes, int n_in,
                              void* d_out, int out_size, void* d_ws, size_t ws_size,
                              hipStream_t stream) {
    const float* in  = (const float*)d_in[0];
    const float* Wm  = (const float*)d_in[1];
    float*       out = (float*)d_out;
    hipLaunchKernelGGL(rcu_kernel, dim3(8 * TILES_PER_B), dim3(512), 0, stream,
                       in, Wm, out);
}

// Round 9
// 204.686 us; speedup vs baseline: 1.1754x; 1.0211x over previous
//
#include <hip/hip_runtime.h>

// Problem: B=8, C=256, T=16, H=28, W=28
//   h_t = 0.5*(W @ h_{t-1} + x_t)   (channel matmul per spatial position)
//   out[:,:,0] = x0; out[:,:,t] = h_t
//
// Round-6 structure (32-col tiles, 200 blocks x 512 threads, x in registers
// 1 step ahead, h in double-buffered bf16 LDS, lgkmcnt-only barriers,
// plain stores -- NT stores reverted, they cost 4% and inflated WRITE).
//
// THIS VERSION (single axis): BATCH -> XCD CLUSTERING.
// Seven CU-side variants all pin at 2.2-2.5 TB/s: the cap is in the DRAM
// address stream. Each 3136 B (c,t)-row is split across the 25 column-tile
// blocks of one batch; with default round-robin dispatch those 25 blocks sit
// on 8 DIFFERENT XCDs, so one row's 25 sequential 128 B lines reach the
// memory controller thousands of unrelated lines apart -> no page hits,
// activate-bound DRAM at ~1/3 streaming rate. Remap bid -> (b=bid%8,
// j=bid/8): under XCD = bid%8 round-robin, ALL 25 tiles of batch b land on
// XCD b, same-row requests cluster within one XCD's issue window, and the
// DRAM scheduler can merge them into page-hit bursts (reads and writes).

typedef __attribute__((ext_vector_type(8))) short bf16x8;  // 8 bf16 = 4 VGPRs
typedef __attribute__((ext_vector_type(4))) float f32x4;
typedef __attribute__((ext_vector_type(4))) short short4v;

#define TILES_PER_B 25   // 24 full 32-col tiles + 1 tail 16-col tile
#define LDSK 264         // 256 + 8 bf16 pad -> row stride 528 B

// Raw LDS-only barrier: drain this wave's LDS ops, then s_barrier.
// NO vmcnt drain -- in-flight global loads/stores survive the barrier.
#define LDS_BARRIER()                                                          \
    do {                                                                       \
        asm volatile("s_waitcnt lgkmcnt(0)" ::: "memory");                     \
        __builtin_amdgcn_s_barrier();                                          \
        __builtin_amdgcn_sched_barrier(0);                                     \
    } while (0)

__device__ __forceinline__ short f2bf(float f) {
    // round-to-nearest-even fp32 -> bf16 (inputs finite)
    union { float f; unsigned u; } v; v.f = f;
    unsigned r = v.u + 0x7FFFu + ((v.u >> 16) & 1u);
    return (short)(r >> 16);
}

// NT = number of 16-col n-tiles this block owns (2 = full 32-col, 1 = tail).
template <int NT>
__device__ __forceinline__ void run_tile(const float* __restrict__ xin,
                                         float* __restrict__ xout,
                                         const float* __restrict__ Wm,
                                         short (*hbuf)[32][LDSK]) {
    const int tid  = threadIdx.x;
    const int wave = tid >> 6;      // 8 waves: wave w owns channels [w*32, w*32+32)
    const int lane = tid & 63;
    const int l15  = lane & 15;
    const int quad = lane >> 4;

    // ---- Preload W as bf16 A-fragments (once; reused for all 15 steps) ----
    // A[m][k]: m = lane&15 (+tile base), k = quad*8 + j
    bf16x8 a_frag[2][8];            // 2 m-tiles x 8 k-steps = 64 VGPRs
#pragma unroll
    for (int mt = 0; mt < 2; ++mt) {
        const int m = wave * 32 + mt * 16 + l15;
        const float* wrow = Wm + m * 256 + quad * 8;
#pragma unroll
        for (int ks = 0; ks < 8; ++ks) {
            float4 f0 = *(const float4*)(wrow + ks * 32);
            float4 f1 = *(const float4*)(wrow + ks * 32 + 4);
            bf16x8 a;
            a[0] = f2bf(f0.x); a[1] = f2bf(f0.y); a[2] = f2bf(f0.z); a[3] = f2bf(f0.w);
            a[4] = f2bf(f1.x); a[5] = f2bf(f1.y); a[6] = f2bf(f1.z); a[7] = f2bf(f1.w);
            a_frag[mt][ks] = a;
        }
    }

    // ---- Init: h0 = x(t=0); passthrough to out; stage bf16 into hbuf[0] ----
    {
        const int NS  = 16 * NT;          // spatial width of this tile
        const int sg  = tid & (NS - 1);   // spatial within tile
        const int cg  = tid / NS;         // channel group
        const int CPT = NS / 2;           // channels per thread (16 or 8)
#pragma unroll
        for (int i = 0; i < CPT; ++i) {
            const int c = cg * CPT + i;
            const size_t off = (size_t)c * 12544 + sg;   // t = 0
            const float v = xin[off];
            xout[off] = v;
            hbuf[0][sg][c] = f2bf(v);
        }
    }

    // x value ring, 1-step prefetch depth; all indices static after unroll.
    // slot (mt,nt,r) -> channel c = wave*32 + mt*16 + quad*4 + r,
    //                   spatial s = nt*16 + l15
    float xr[2][2][NT][4];

    // preload x(t=1)
#pragma unroll
    for (int mt = 0; mt < 2; ++mt)
#pragma unroll
        for (int nt = 0; nt < NT; ++nt)
#pragma unroll
            for (int r = 0; r < 4; ++r) {
                const int c = wave * 32 + mt * 16 + quad * 4 + r;
                xr[1][mt][nt][r] = xin[((size_t)c * 16 + 1) * 784 + nt * 16 + l15];
            }

    // publish hbuf[0] (cross-wave); init stores/loads stay in flight
    LDS_BARRIER();

    int cur = 0;
#pragma unroll
    for (int t = 1; t < 16; ++t) {
        const int xb = t & 1;        // xr slot holding x(t)

        // ---- prefetch x(t+1) into the other ring slot (plain global loads;
        //      retired ~one full step later by the compiler's counted vmcnt)
        if (t < 15) {
#pragma unroll
            for (int mt = 0; mt < 2; ++mt)
#pragma unroll
                for (int nt = 0; nt < NT; ++nt)
#pragma unroll
                    for (int r = 0; r < 4; ++r) {
                        const int c = wave * 32 + mt * 16 + quad * 4 + r;
                        xr[xb ^ 1][mt][nt][r] =
                            xin[((size_t)c * 16 + t + 1) * 784 + nt * 16 + l15];
                    }
        }

        // B fragments from LDS: B[k][n], k = ks*32 + quad*8 + j,
        // n = nt*16 + (lane&15)
        bf16x8 bfrag[NT][8];
#pragma unroll
        for (int nt = 0; nt < NT; ++nt) {
            const short* hp = &hbuf[cur][nt * 16 + l15][quad * 8];
#pragma unroll
            for (int ks = 0; ks < 8; ++ks)
                bfrag[nt][ks] = *(const bf16x8*)(hp + ks * 32);   // ds_read_b128
        }

        f32x4 acc[2][NT];
#pragma unroll
        for (int mt = 0; mt < 2; ++mt)
#pragma unroll
            for (int nt = 0; nt < NT; ++nt) {
                acc[mt][nt] = (f32x4){0.f, 0.f, 0.f, 0.f};
#pragma unroll
                for (int ks = 0; ks < 8; ++ks)
                    acc[mt][nt] = __builtin_amdgcn_mfma_f32_16x16x32_bf16(
                        a_frag[mt][ks], bfrag[nt][ks], acc[mt][nt], 0, 0, 0);
            }

        const int nxt = cur ^ 1;
#pragma unroll
        for (int mt = 0; mt < 2; ++mt) {
            // D layout: row(channel within tile) = quad*4 + r, col = lane&15
            const int c0 = wave * 32 + mt * 16 + quad * 4;
#pragma unroll
            for (int nt = 0; nt < NT; ++nt) {
                short4v hbf;
#pragma unroll
                for (int r = 0; r < 4; ++r) {
                    const float v = 0.5f * (acc[mt][nt][r] + xr[xb][mt][nt][r]);
                    xout[((size_t)(c0 + r) * 16 + t) * 784 + nt * 16 + l15] = v;
                    hbf[r] = f2bf(v);
                }
                // 4 consecutive channels -> one 8B LDS write
                *(short4v*)&hbuf[nxt][nt * 16 + l15][c0] = hbf;
            }
        }
        // Publish hbuf[nxt]; in-flight loads + stores survive the barrier.
        LDS_BARRIER();
        cur = nxt;
    }
}

__global__ __launch_bounds__(512, 2)
void rcu_kernel(const float* __restrict__ in, const float* __restrict__ Wm,
                float* __restrict__ out) {
    // h double-buffer, bf16 [n=32][k=256(+8)] : 33792 B (only LDS use)
    __shared__ short hbuf[2][32][LDSK];

    // Batch->XCD clustering: under round-robin dispatch (XCD = blockIdx%8),
    // batch b = blockIdx%8 puts all 25 tiles of a batch on one XCD, so the
    // 25 blocks sharing each 3136 B (c,t)-row issue their sequential 128 B
    // lines within one XCD's window -> DRAM page-hit bursts.
    const int b = blockIdx.x & 7;          // batch  (= XCD under round-robin)
    const int j = blockIdx.x >> 3;         // column tile 0..24
    const size_t base = (size_t)b * 256 * 16 * 784 + (size_t)j * 32;

    if (j < 24) run_tile<2>(in + base, out + base, Wm, hbuf);
    else        run_tile<1>(in + base, out + base, Wm, hbuf);
}

extern "C" void kernel_launch(void* const* d_in, const int* in_sizes, int n_in,
                              void* d_out, int out_size, void* d_ws, size_t ws_size,
                              hipStream_t stream) {
    const float* in  = (const float*)d_in[0];
    const float* Wm  = (const float*)d_in[1];
    float*       out = (float*)d_out;
    hipLaunchKernelGGL(rcu_kernel, dim3(8 * TILES_PER_B), dim3(512), 0, stream,
                       in, Wm, out);
}